// Round 2
// baseline (523.218 us; speedup 1.0000x reference)
//
#include <hip/hip_runtime.h>
#include <stdint.h>
#include <math.h>

#ifndef M_PI
#define M_PI 3.14159265358979323846
#endif

// Problem constants (fixed by setup_inputs)
#define B_ 2
#define N_ 4
#define H_ 256
#define W_ 512
#define C_ 12
#define HW_ (H_*W_)          // 131072 = 2^17
#define P_ (N_*HW_)          // 524288 = 2^19
#define BP_ (B_*P_)          // 1048576
#define EMPTY_KEY 0xFFFFFFFFu
#define INVALID_ENTRY 0xFFFFFFFFu

__device__ __forceinline__ uint32_t mix32(uint32_t k) {
    k ^= k >> 16; k *= 0x85ebca6bu;
    k ^= k >> 13; k *= 0xc2b2ae35u;
    k ^= k >> 16;
    return k;
}

// Pass 0: per-row/per-column trig tables (bitwise-identical hoist of pass1 math).
// tab layout: [0 .. W_) : sin_lon   [W_ .. 2W) : cos_lon
//             [2W .. 2W+H) : cos_lat  [2W+H .. 2W+2H) : sin_nlat
__global__ __launch_bounds__(256) void k_dirs(
    const int* __restrict__ p_imh, const int* __restrict__ p_imw,
    float* __restrict__ tab)
{
    int i = blockIdx.x * blockDim.x + threadIdx.x;
    int imh = *p_imh, imw = *p_imw;
    float fxf = (float)((double)imw / (2.0 * M_PI));
    float fyf = (float)(-(double)imh / M_PI);
    float cxf = (float)imw * 0.5f;
    float cyf = (float)imh * 0.5f;
    if (i < W_) {
        float lon = __fdiv_rn(__fsub_rn(__fadd_rn((float)i, 0.5f), cxf), fxf);
        double dlon = (double)lon;
        tab[i]       = (float)sin(dlon);
        tab[W_ + i]  = (float)cos(dlon);
    } else if (i < W_ + H_) {
        int h = i - W_;
        float lat = __fdiv_rn(__fsub_rn(__fadd_rn((float)h, 0.5f), cyf), fyf);
        double dlat = (double)lat;
        tab[2*W_ + h]       = (float)cos(dlat);
        tab[2*W_ + H_ + h]  = (float)sin(-dlat);
    }
}

// Pass 1: compute means, vid, score; insert into hash table; atomicMax slot0.
__global__ __launch_bounds__(256) void k_pass1(
    const float* __restrict__ depth,
    const float* __restrict__ opacity,
    const float* __restrict__ confidence,
    const float* __restrict__ poses,
    const float* __restrict__ tab,
    uint32_t* __restrict__ keys,
    unsigned long long* __restrict__ slot0,
    unsigned long long* __restrict__ packed_arr,
    uint32_t* __restrict__ entry_arr,
    float* __restrict__ mx, float* __restrict__ my, float* __restrict__ mz,
    uint32_t tmask)
{
    int g = blockIdx.x * blockDim.x + threadIdx.x;
    if (g >= BP_) return;
    int b  = g >> 19;           // / P_
    int p  = g & (P_ - 1);
    int n  = p >> 17;           // / HW_
    int hw = p & (HW_ - 1);
    int h  = hw >> 9;           // / W_
    int w  = hw & (W_ - 1);

    float sin_lon  = tab[w];
    float cos_lon  = tab[W_ + w];
    float cos_lat  = tab[2*W_ + h];
    float sin_nlat = tab[2*W_ + H_ + h];

    float dx = __fmul_rn(cos_lat, sin_lon);
    float dy = sin_nlat;
    float dz = __fmul_rn(cos_lat, cos_lon);

    float d = depth[g];
    float pc0 = __fmul_rn(d, dx);
    float pc1 = __fmul_rn(d, dy);
    float pc2 = __fmul_rn(d, dz);

    const float* Pz = poses + (size_t)(b * N_ + n) * 16;
    float m[3];
#pragma unroll
    for (int i = 0; i < 3; ++i) {
        // einsum left-to-right, no FMA, then + t  (match jnp f32 semantics)
        float s = __fmul_rn(Pz[i*4+0], pc0);
        s = __fadd_rn(s, __fmul_rn(Pz[i*4+1], pc1));
        s = __fadd_rn(s, __fmul_rn(Pz[i*4+2], pc2));
        s = __fadd_rn(s, Pz[i*4+3]);
        m[i] = s;
    }
    mx[g] = m[0]; my[g] = m[1]; mz[g] = m[2];

    float conf = confidence[g];
    float opac = opacity[g];
    bool valid = (conf > 0.1f) && (opac > 0.01f);

    unsigned long long pk = 0ull;
    uint32_t e = INVALID_ENTRY;
    if (valid) {
        int vc[3];
#pragma unroll
        for (int i = 0; i < 3; ++i) {
            float q  = __fdiv_rn(m[i], 0.1f);
            float fq = floorf(q);
            int vi = (int)fq + 512;
            vi = vi < 0 ? 0 : (vi > 1023 ? 1023 : vi);
            vc[i] = vi;
        }
        uint32_t vid = ((uint32_t)vc[0] << 20) | ((uint32_t)vc[1] << 10) | (uint32_t)vc[2];
        float score = __fadd_rn(__fmul_rn(0.7f, conf), __fmul_rn(0.3f, opac));
        // higher score wins; ties -> smaller per-batch index (stable-sort order)
        pk = ((unsigned long long)__float_as_uint(score) << 32)
           | (unsigned long long)(~(uint32_t)p);

        uint32_t key  = vid | ((uint32_t)b << 30);
        uint32_t slot = mix32(key) & tmask;
        while (true) {
            uint32_t prev = atomicCAS(&keys[slot], EMPTY_KEY, key);
            if (prev == EMPTY_KEY || prev == key) break;
            slot = (slot + 1) & tmask;
        }
        atomicMax(&slot0[slot], pk);
        e = slot;
    }
    packed_arr[g] = pk;
    entry_arr[g]  = e;
}

// Pass 2: second max per voxel.
__global__ __launch_bounds__(256) void k_pass2(
    const unsigned long long* __restrict__ packed_arr,
    const uint32_t* __restrict__ entry_arr,
    const unsigned long long* __restrict__ slot0,
    unsigned long long* __restrict__ slot1)
{
    int g = blockIdx.x * blockDim.x + threadIdx.x;
    if (g >= BP_) return;
    uint32_t e = entry_arr[g];
    if (e == INVALID_ENTRY) return;
    unsigned long long pk = packed_arr[g];
    if (pk != slot0[e]) atomicMax(&slot1[e], pk);
}

// Pass 3: selection + gather + write features and sel flag.
__global__ __launch_bounds__(256) void k_pass3(
    const float* __restrict__ covariance,
    const float* __restrict__ rotation,
    const float* __restrict__ opacity,
    const float* __restrict__ sh_color,
    const float* __restrict__ confidence,
    const unsigned long long* __restrict__ packed_arr,
    const uint32_t* __restrict__ entry_arr,
    const unsigned long long* __restrict__ slot0,
    const unsigned long long* __restrict__ slot1,
    const float* __restrict__ mx, const float* __restrict__ my, const float* __restrict__ mz,
    float* __restrict__ out)
{
    int g = blockIdx.x * blockDim.x + threadIdx.x;
    if (g >= BP_) return;
    int b  = g >> 19;
    int p  = g & (P_ - 1);
    int n  = p >> 17;
    int hw = p & (HW_ - 1);

    uint32_t e = entry_arr[g];
    bool sel = false;
    if (e != INVALID_ENTRY) {
        unsigned long long pk = packed_arr[g];
        sel = (pk == slot0[e]) || (pk == slot1[e]);
    }

    alignas(16) float v[24];
    if (sel) {
        int bn = b * N_ + n;
        const float* cov = covariance + (size_t)bn * 3  * HW_ + hw;
        const float* rot = rotation   + (size_t)bn * 4  * HW_ + hw;
        const float* shc = sh_color   + (size_t)bn * 12 * HW_ + hw;
        v[0] = mx[g]; v[1] = my[g]; v[2] = mz[g];
        v[3] = cov[0]; v[4] = cov[HW_]; v[5] = cov[2*HW_];
        v[6] = rot[0]; v[7] = rot[HW_]; v[8] = rot[2*HW_]; v[9] = rot[3*HW_];
        v[10] = opacity[g];
#pragma unroll
        for (int c = 0; c < 12; ++c) v[11 + c] = shc[(size_t)c * HW_];
        v[23] = confidence[g];
    } else {
#pragma unroll
        for (int i = 0; i < 24; ++i) v[i] = 0.0f;
    }

    float4* o = (float4*)(out + (size_t)g * 24);
#pragma unroll
    for (int i = 0; i < 6; ++i) o[i] = ((const float4*)v)[i];

    out[(size_t)BP_ * 24 + g] = sel ? 1.0f : 0.0f;
}

extern "C" void kernel_launch(void* const* d_in, const int* in_sizes, int n_in,
                              void* d_out, int out_size, void* d_ws, size_t ws_size,
                              hipStream_t stream)
{
    const float* depth      = (const float*)d_in[0];
    const float* covariance = (const float*)d_in[1];
    const float* rotation   = (const float*)d_in[2];
    const float* opacity    = (const float*)d_in[3];
    const float* sh_color   = (const float*)d_in[4];
    const float* confidence = (const float*)d_in[5];
    const float* poses      = (const float*)d_in[6];
    const int*   imh        = (const int*)d_in[7];
    const int*   imw        = (const int*)d_in[8];
    float* out = (float*)d_out;

    // workspace layout:
    // [keys T*4][slot0 T*8][slot1 T*8][packed BP*8][entry BP*4][mx,my,mz BP*4 each][tab 6KB]
    size_t tab_bytes = (size_t)(2*W_ + 2*H_) * 4;
    size_t fixed_bytes = (size_t)BP_ * (8 + 4 + 12) + tab_bytes;
    size_t T = (size_t)1 << 21;
    while (T > ((size_t)1 << 18) && fixed_bytes + T * 20 > ws_size) T >>= 1;

    char* w = (char*)d_ws;
    uint32_t* keys               = (uint32_t*)w;           w += T * 4;
    unsigned long long* slot0    = (unsigned long long*)w; w += T * 8;
    unsigned long long* slot1    = (unsigned long long*)w; w += T * 8;
    unsigned long long* packed_a = (unsigned long long*)w; w += (size_t)BP_ * 8;
    uint32_t* entry_a            = (uint32_t*)w;           w += (size_t)BP_ * 4;
    float* mx = (float*)w;                                 w += (size_t)BP_ * 4;
    float* my = (float*)w;                                 w += (size_t)BP_ * 4;
    float* mz = (float*)w;                                 w += (size_t)BP_ * 4;
    float* tab = (float*)w;                                w += tab_bytes;

    // re-init table every call (ws is poisoned 0xAA before each timed launch)
    hipMemsetAsync(keys, 0xFF, T * 4, stream);
    hipMemsetAsync(slot0, 0x00, T * 16, stream);   // slot0+slot1 contiguous

    dim3 blk(256);
    hipLaunchKernelGGL(k_dirs, dim3((2*W_ + 2*H_ + 255) / 256), blk, 0, stream,
                       imh, imw, tab);

    dim3 grd(BP_ / 256);
    hipLaunchKernelGGL(k_pass1, grd, blk, 0, stream,
                       depth, opacity, confidence, poses, tab,
                       keys, slot0, packed_a, entry_a, mx, my, mz, (uint32_t)(T - 1));
    hipLaunchKernelGGL(k_pass2, grd, blk, 0, stream,
                       packed_a, entry_a, slot0, slot1);
    hipLaunchKernelGGL(k_pass3, grd, blk, 0, stream,
                       covariance, rotation, opacity, sh_color, confidence,
                       packed_a, entry_a, slot0, slot1, mx, my, mz, out);
}

// Round 3
// 486.129 us; speedup vs baseline: 1.0763x; 1.0763x over previous
//
#include <hip/hip_runtime.h>
#include <stdint.h>
#include <math.h>

#ifndef M_PI
#define M_PI 3.14159265358979323846
#endif

// Problem constants (fixed by setup_inputs)
#define B_ 2
#define N_ 4
#define H_ 256
#define W_ 512
#define C_ 12
#define HW_ (H_*W_)          // 131072 = 2^17
#define P_ (N_*HW_)          // 524288 = 2^19
#define BP_ (B_*P_)          // 1048576
#define EMPTY_KEY 0xFFFFFFFFu
#define INVALID_ENTRY 0xFFFFFFFFu

__device__ __forceinline__ uint32_t mix32(uint32_t k) {
    k ^= k >> 16; k *= 0x85ebca6bu;
    k ^= k >> 13; k *= 0xc2b2ae35u;
    k ^= k >> 16;
    return k;
}

// Shared math: means + pk recomputed bit-identically in pass1 and pass3.
__device__ __forceinline__ void compute_means(
    int b, int n, float d, const float* __restrict__ tab,
    const float* __restrict__ poses, int h, int w, float m[3])
{
    float sin_lon  = tab[w];
    float cos_lon  = tab[W_ + w];
    float cos_lat  = tab[2*W_ + h];
    float sin_nlat = tab[2*W_ + H_ + h];

    float pc0 = __fmul_rn(d, __fmul_rn(cos_lat, sin_lon));
    float pc1 = __fmul_rn(d, sin_nlat);
    float pc2 = __fmul_rn(d, __fmul_rn(cos_lat, cos_lon));

    const float* Pz = poses + (size_t)(b * N_ + n) * 16;
#pragma unroll
    for (int i = 0; i < 3; ++i) {
        // einsum left-to-right, no FMA, then + t  (match jnp f32 semantics)
        float s = __fmul_rn(Pz[i*4+0], pc0);
        s = __fadd_rn(s, __fmul_rn(Pz[i*4+1], pc1));
        s = __fadd_rn(s, __fmul_rn(Pz[i*4+2], pc2));
        s = __fadd_rn(s, Pz[i*4+3]);
        m[i] = s;
    }
}

__device__ __forceinline__ unsigned long long make_pk(float conf, float opac, int p) {
    float score = __fadd_rn(__fmul_rn(0.7f, conf), __fmul_rn(0.3f, opac));
    // higher score wins; ties -> smaller per-batch index (stable-sort order)
    return ((unsigned long long)__float_as_uint(score) << 32)
         | (unsigned long long)(~(uint32_t)p);
}

// Pass 0: per-row/per-column trig tables (bitwise-identical hoist).
// tab layout: [0..W): sin_lon  [W..2W): cos_lon  [2W..2W+H): cos_lat  [2W+H..2W+2H): sin_nlat
__global__ __launch_bounds__(256) void k_dirs(
    const int* __restrict__ p_imh, const int* __restrict__ p_imw,
    float* __restrict__ tab)
{
    int i = blockIdx.x * blockDim.x + threadIdx.x;
    int imh = *p_imh, imw = *p_imw;
    float fxf = (float)((double)imw / (2.0 * M_PI));
    float fyf = (float)(-(double)imh / M_PI);
    float cxf = (float)imw * 0.5f;
    float cyf = (float)imh * 0.5f;
    if (i < W_) {
        float lon = __fdiv_rn(__fsub_rn(__fadd_rn((float)i, 0.5f), cxf), fxf);
        double dlon = (double)lon;
        tab[i]       = (float)sin(dlon);
        tab[W_ + i]  = (float)cos(dlon);
    } else if (i < W_ + H_) {
        int h = i - W_;
        float lat = __fdiv_rn(__fsub_rn(__fadd_rn((float)h, 0.5f), cyf), fyf);
        double dlat = (double)lat;
        tab[2*W_ + h]       = (float)cos(dlat);
        tab[2*W_ + H_ + h]  = (float)sin(-dlat);
    }
}

// Pass 1: hash-insert + guarded top-2 waterfall. Writes only entry_arr.
// slots[e] = {slot0, slot1} interleaved (one 64B-line pair).
__global__ __launch_bounds__(256) void k_pass1(
    const float* __restrict__ depth,
    const float* __restrict__ opacity,
    const float* __restrict__ confidence,
    const float* __restrict__ poses,
    const float* __restrict__ tab,
    uint32_t* __restrict__ keys,
    ulonglong2* __restrict__ slots,
    uint32_t* __restrict__ entry_arr,
    uint32_t tmask)
{
    int g = blockIdx.x * blockDim.x + threadIdx.x;
    if (g >= BP_) return;
    int b  = g >> 19;           // / P_
    int p  = g & (P_ - 1);
    int n  = p >> 17;           // / HW_
    int hw = p & (HW_ - 1);
    int h  = hw >> 9;           // / W_
    int w  = hw & (W_ - 1);

    float conf = confidence[g];
    float opac = opacity[g];
    bool valid = (conf > 0.1f) && (opac > 0.01f);

    uint32_t e = INVALID_ENTRY;
    if (valid) {
        float m[3];
        compute_means(b, n, depth[g], tab, poses, h, w, m);

        int vc[3];
#pragma unroll
        for (int i = 0; i < 3; ++i) {
            float q  = __fdiv_rn(m[i], 0.1f);
            float fq = floorf(q);
            int vi = (int)fq + 512;
            vi = vi < 0 ? 0 : (vi > 1023 ? 1023 : vi);
            vc[i] = vi;
        }
        uint32_t vid = ((uint32_t)vc[0] << 20) | ((uint32_t)vc[1] << 10) | (uint32_t)vc[2];
        unsigned long long pk = make_pk(conf, opac, p);

        uint32_t key  = vid | ((uint32_t)b << 30);
        uint32_t slot = mix32(key) & tmask;
        while (true) {
            uint32_t prev = atomicCAS(&keys[slot], EMPTY_KEY, key);
            if (prev == EMPTY_KEY || prev == key) break;
            slot = (slot + 1) & tmask;
        }
        e = slot;

        unsigned long long* s0p = &slots[slot].x;
        unsigned long long* s1p = &slots[slot].y;

        // Guarded waterfall. Stale plain loads only under-estimate (monotone) -> safe.
        unsigned long long low = pk;
        unsigned long long s0 = *(const volatile unsigned long long*)s0p;
        if (pk > s0) {
            unsigned long long old = atomicMax(s0p, pk);
            low = old < pk ? old : pk;   // displaced value
        }
        if (low != 0ull) {
            unsigned long long s1 = *(const volatile unsigned long long*)s1p;
            if (low > s1) atomicMax(s1p, low);
        }
    }
    entry_arr[g] = e;
}

// Pass 3: recompute means/pk, selection via slot pair, gather + write.
__global__ __launch_bounds__(256) void k_pass3(
    const float* __restrict__ depth,
    const float* __restrict__ covariance,
    const float* __restrict__ rotation,
    const float* __restrict__ opacity,
    const float* __restrict__ sh_color,
    const float* __restrict__ confidence,
    const float* __restrict__ poses,
    const float* __restrict__ tab,
    const uint32_t* __restrict__ entry_arr,
    const ulonglong2* __restrict__ slots,
    float* __restrict__ out)
{
    int g = blockIdx.x * blockDim.x + threadIdx.x;
    if (g >= BP_) return;
    int b  = g >> 19;
    int p  = g & (P_ - 1);
    int n  = p >> 17;
    int hw = p & (HW_ - 1);
    int h  = hw >> 9;
    int w  = hw & (W_ - 1);

    float conf = confidence[g];
    float opac = opacity[g];

    uint32_t e = entry_arr[g];
    bool sel = false;
    if (e != INVALID_ENTRY) {
        unsigned long long pk = make_pk(conf, opac, p);
        ulonglong2 sp = slots[e];
        sel = (pk == sp.x) || (pk == sp.y);
    }

    alignas(16) float v[24];
    if (sel) {
        float m[3];
        compute_means(b, n, depth[g], tab, poses, h, w, m);
        int bn = b * N_ + n;
        const float* cov = covariance + (size_t)bn * 3  * HW_ + hw;
        const float* rot = rotation   + (size_t)bn * 4  * HW_ + hw;
        const float* shc = sh_color   + (size_t)bn * 12 * HW_ + hw;
        v[0] = m[0]; v[1] = m[1]; v[2] = m[2];
        v[3] = cov[0]; v[4] = cov[HW_]; v[5] = cov[2*HW_];
        v[6] = rot[0]; v[7] = rot[HW_]; v[8] = rot[2*HW_]; v[9] = rot[3*HW_];
        v[10] = opac;
#pragma unroll
        for (int c = 0; c < 12; ++c) v[11 + c] = shc[(size_t)c * HW_];
        v[23] = conf;
    } else {
#pragma unroll
        for (int i = 0; i < 24; ++i) v[i] = 0.0f;
    }

    float4* o = (float4*)(out + (size_t)g * 24);
#pragma unroll
    for (int i = 0; i < 6; ++i) o[i] = ((const float4*)v)[i];

    out[(size_t)BP_ * 24 + g] = sel ? 1.0f : 0.0f;
}

extern "C" void kernel_launch(void* const* d_in, const int* in_sizes, int n_in,
                              void* d_out, int out_size, void* d_ws, size_t ws_size,
                              hipStream_t stream)
{
    const float* depth      = (const float*)d_in[0];
    const float* covariance = (const float*)d_in[1];
    const float* rotation   = (const float*)d_in[2];
    const float* opacity    = (const float*)d_in[3];
    const float* sh_color   = (const float*)d_in[4];
    const float* confidence = (const float*)d_in[5];
    const float* poses      = (const float*)d_in[6];
    const int*   imh        = (const int*)d_in[7];
    const int*   imw        = (const int*)d_in[8];
    float* out = (float*)d_out;

    // workspace layout: [keys T*4][slots T*16][entry BP*4][tab 6KB]
    size_t tab_bytes = (size_t)(2*W_ + 2*H_) * 4;
    size_t fixed_bytes = (size_t)BP_ * 4 + tab_bytes;
    size_t T = (size_t)1 << 21;
    while (T > ((size_t)1 << 18) && fixed_bytes + T * 20 > ws_size) T >>= 1;

    char* wp = (char*)d_ws;
    uint32_t* keys     = (uint32_t*)wp;   wp += T * 4;
    ulonglong2* slots  = (ulonglong2*)wp; wp += T * 16;
    uint32_t* entry_a  = (uint32_t*)wp;   wp += (size_t)BP_ * 4;
    float* tab = (float*)wp;              wp += tab_bytes;

    // re-init table every call (ws is poisoned 0xAA before each timed launch)
    hipMemsetAsync(keys, 0xFF, T * 4, stream);
    hipMemsetAsync(slots, 0x00, T * 16, stream);

    dim3 blk(256);
    hipLaunchKernelGGL(k_dirs, dim3((2*W_ + 2*H_ + 255) / 256), blk, 0, stream,
                       imh, imw, tab);

    dim3 grd(BP_ / 256);
    hipLaunchKernelGGL(k_pass1, grd, blk, 0, stream,
                       depth, opacity, confidence, poses, tab,
                       keys, slots, entry_a, (uint32_t)(T - 1));
    hipLaunchKernelGGL(k_pass3, grd, blk, 0, stream,
                       depth, covariance, rotation, opacity, sh_color, confidence,
                       poses, tab, entry_a, slots, out);
}

// Round 4
// 445.149 us; speedup vs baseline: 1.1754x; 1.0921x over previous
//
#include <hip/hip_runtime.h>
#include <stdint.h>
#include <math.h>

#ifndef M_PI
#define M_PI 3.14159265358979323846
#endif

// Problem constants (fixed by setup_inputs)
#define B_ 2
#define N_ 4
#define H_ 256
#define W_ 512
#define C_ 12
#define HW_ (H_*W_)          // 131072 = 2^17
#define P_ (N_*HW_)          // 524288 = 2^19
#define BP_ (B_*P_)          // 1048576
#define INVALID_ENTRY 0xFFFFFFFFu

__device__ __forceinline__ uint32_t mix32(uint32_t k) {
    k ^= k >> 16; k *= 0x85ebca6bu;
    k ^= k >> 13; k *= 0xc2b2ae35u;
    k ^= k >> 16;
    return k;
}

// Shared math: means + pk recomputed bit-identically in pass1 and pass3.
__device__ __forceinline__ void compute_means(
    int b, int n, float d, const float* __restrict__ tab,
    const float* __restrict__ poses, int h, int w, float m[3])
{
    float sin_lon  = tab[w];
    float cos_lon  = tab[W_ + w];
    float cos_lat  = tab[2*W_ + h];
    float sin_nlat = tab[2*W_ + H_ + h];

    float pc0 = __fmul_rn(d, __fmul_rn(cos_lat, sin_lon));
    float pc1 = __fmul_rn(d, sin_nlat);
    float pc2 = __fmul_rn(d, __fmul_rn(cos_lat, cos_lon));

    const float* Pz = poses + (size_t)(b * N_ + n) * 16;
#pragma unroll
    for (int i = 0; i < 3; ++i) {
        // einsum left-to-right, no FMA, then + t  (match jnp f32 semantics)
        float s = __fmul_rn(Pz[i*4+0], pc0);
        s = __fadd_rn(s, __fmul_rn(Pz[i*4+1], pc1));
        s = __fadd_rn(s, __fmul_rn(Pz[i*4+2], pc2));
        s = __fadd_rn(s, Pz[i*4+3]);
        m[i] = s;
    }
}

__device__ __forceinline__ unsigned long long make_pk(float conf, float opac, int p) {
    float score = __fadd_rn(__fmul_rn(0.7f, conf), __fmul_rn(0.3f, opac));
    // higher score wins; ties -> smaller per-batch index (stable-sort order)
    return ((unsigned long long)__float_as_uint(score) << 32)
         | (unsigned long long)(~(uint32_t)p);
}

// Pass 0: per-row/per-column trig tables (bitwise-identical hoist).
// tab layout: [0..W): sin_lon  [W..2W): cos_lon  [2W..2W+H): cos_lat  [2W+H..2W+2H): sin_nlat
__global__ __launch_bounds__(256) void k_dirs(
    const int* __restrict__ p_imh, const int* __restrict__ p_imw,
    float* __restrict__ tab)
{
    int i = blockIdx.x * blockDim.x + threadIdx.x;
    int imh = *p_imh, imw = *p_imw;
    float fxf = (float)((double)imw / (2.0 * M_PI));
    float fyf = (float)(-(double)imh / M_PI);
    float cxf = (float)imw * 0.5f;
    float cyf = (float)imh * 0.5f;
    if (i < W_) {
        float lon = __fdiv_rn(__fsub_rn(__fadd_rn((float)i, 0.5f), cxf), fxf);
        double dlon = (double)lon;
        tab[i]       = (float)sin(dlon);
        tab[W_ + i]  = (float)cos(dlon);
    } else if (i < W_ + H_) {
        int h = i - W_;
        float lat = __fdiv_rn(__fsub_rn(__fadd_rn((float)h, 0.5f), cyf), fyf);
        double dlat = (double)lat;
        tab[2*W_ + h]       = (float)cos(dlat);
        tab[2*W_ + H_ + h]  = (float)sin(-dlat);
    }
}

// Pass 1: guarded hash-insert + guarded top-2 waterfall. Writes only entry_arr.
// keys: 0 = empty (real keys always have bit31 set). slots[e] = {s0, s1}.
// All guards use PLAIN cached loads: slot values / keys are monotone, so a
// stale read only under-estimates -> guard only under-skips -> safe.
__global__ __launch_bounds__(256) void k_pass1(
    const float* __restrict__ depth,
    const float* __restrict__ opacity,
    const float* __restrict__ confidence,
    const float* __restrict__ poses,
    const float* __restrict__ tab,
    uint32_t* __restrict__ keys,
    ulonglong2* __restrict__ slots,
    uint32_t* __restrict__ entry_arr,
    uint32_t tmask)
{
    int g = blockIdx.x * blockDim.x + threadIdx.x;
    if (g >= BP_) return;
    int b  = g >> 19;           // / P_
    int p  = g & (P_ - 1);
    int n  = p >> 17;           // / HW_
    int hw = p & (HW_ - 1);
    int h  = hw >> 9;           // / W_
    int w  = hw & (W_ - 1);

    float conf = confidence[g];
    float opac = opacity[g];
    bool valid = (conf > 0.1f) && (opac > 0.01f);

    uint32_t e = INVALID_ENTRY;
    if (valid) {
        float m[3];
        compute_means(b, n, depth[g], tab, poses, h, w, m);

        int vc[3];
#pragma unroll
        for (int i = 0; i < 3; ++i) {
            float q  = __fdiv_rn(m[i], 0.1f);
            float fq = floorf(q);
            int vi = (int)fq + 512;
            vi = vi < 0 ? 0 : (vi > 1023 ? 1023 : vi);
            vc[i] = vi;
        }
        uint32_t vid = ((uint32_t)vc[0] << 20) | ((uint32_t)vc[1] << 10) | (uint32_t)vc[2];
        unsigned long long pk = make_pk(conf, opac, p);

        uint32_t key  = vid | ((uint32_t)b << 30) | 0x80000000u;  // never 0
        uint32_t slot = mix32(key) & tmask;
        while (true) {
            uint32_t k = keys[slot];          // plain cached read (guard)
            if (k == key) break;              // common case at high lambda: no CAS
            if (k == 0u) {
                uint32_t prev = atomicCAS(&keys[slot], 0u, key);
                if (prev == 0u || prev == key) break;
                // lost race to a different key -> probe next
            }
            slot = (slot + 1) & tmask;
        }
        e = slot;

        // Guarded top-2 waterfall (one cached 16B read of both slots).
        ulonglong2 sp = slots[slot];          // stale-low safe
        unsigned long long low = pk;
        if (pk > sp.x) {
            unsigned long long old = atomicMax(&slots[slot].x, pk);
            low = old < pk ? old : pk;        // displaced value
        }
        if (low != 0ull && low > sp.y) {
            atomicMax(&slots[slot].y, low);
        }
    }
    entry_arr[g] = e;
}

// Pass 3: recompute means/pk, selection via slot pair, gather + write.
__global__ __launch_bounds__(256) void k_pass3(
    const float* __restrict__ depth,
    const float* __restrict__ covariance,
    const float* __restrict__ rotation,
    const float* __restrict__ opacity,
    const float* __restrict__ sh_color,
    const float* __restrict__ confidence,
    const float* __restrict__ poses,
    const float* __restrict__ tab,
    const uint32_t* __restrict__ entry_arr,
    const ulonglong2* __restrict__ slots,
    float* __restrict__ out)
{
    int g = blockIdx.x * blockDim.x + threadIdx.x;
    if (g >= BP_) return;
    int b  = g >> 19;
    int p  = g & (P_ - 1);
    int n  = p >> 17;
    int hw = p & (HW_ - 1);
    int h  = hw >> 9;
    int w  = hw & (W_ - 1);

    float conf = confidence[g];
    float opac = opacity[g];

    uint32_t e = entry_arr[g];
    bool sel = false;
    if (e != INVALID_ENTRY) {
        unsigned long long pk = make_pk(conf, opac, p);
        ulonglong2 sp = slots[e];
        sel = (pk == sp.x) || (pk == sp.y);
    }

    alignas(16) float v[24];
    if (sel) {
        float m[3];
        compute_means(b, n, depth[g], tab, poses, h, w, m);
        int bn = b * N_ + n;
        const float* cov = covariance + (size_t)bn * 3  * HW_ + hw;
        const float* rot = rotation   + (size_t)bn * 4  * HW_ + hw;
        const float* shc = sh_color   + (size_t)bn * 12 * HW_ + hw;
        v[0] = m[0]; v[1] = m[1]; v[2] = m[2];
        v[3] = cov[0]; v[4] = cov[HW_]; v[5] = cov[2*HW_];
        v[6] = rot[0]; v[7] = rot[HW_]; v[8] = rot[2*HW_]; v[9] = rot[3*HW_];
        v[10] = opac;
#pragma unroll
        for (int c = 0; c < 12; ++c) v[11 + c] = shc[(size_t)c * HW_];
        v[23] = conf;
    } else {
#pragma unroll
        for (int i = 0; i < 24; ++i) v[i] = 0.0f;
    }

    float4* o = (float4*)(out + (size_t)g * 24);
#pragma unroll
    for (int i = 0; i < 6; ++i) o[i] = ((const float4*)v)[i];

    out[(size_t)BP_ * 24 + g] = sel ? 1.0f : 0.0f;
}

extern "C" void kernel_launch(void* const* d_in, const int* in_sizes, int n_in,
                              void* d_out, int out_size, void* d_ws, size_t ws_size,
                              hipStream_t stream)
{
    const float* depth      = (const float*)d_in[0];
    const float* covariance = (const float*)d_in[1];
    const float* rotation   = (const float*)d_in[2];
    const float* opacity    = (const float*)d_in[3];
    const float* sh_color   = (const float*)d_in[4];
    const float* confidence = (const float*)d_in[5];
    const float* poses      = (const float*)d_in[6];
    const int*   imh        = (const int*)d_in[7];
    const int*   imw        = (const int*)d_in[8];
    float* out = (float*)d_out;

    // workspace layout: [keys T*4][slots T*16][entry BP*4][tab 6KB]
    size_t tab_bytes = (size_t)(2*W_ + 2*H_) * 4;
    size_t fixed_bytes = (size_t)BP_ * 4 + tab_bytes;
    size_t T = (size_t)1 << 21;
    while (T > ((size_t)1 << 18) && fixed_bytes + T * 20 > ws_size) T >>= 1;

    char* wp = (char*)d_ws;
    uint32_t* keys     = (uint32_t*)wp;   wp += T * 4;
    ulonglong2* slots  = (ulonglong2*)wp; wp += T * 16;
    uint32_t* entry_a  = (uint32_t*)wp;   wp += (size_t)BP_ * 4;
    float* tab = (float*)wp;              wp += tab_bytes;

    // keys empty = 0 and slots zero -> one contiguous memset (keys+slots adjacent)
    hipMemsetAsync(d_ws, 0x00, T * 20, stream);

    dim3 blk(256);
    hipLaunchKernelGGL(k_dirs, dim3((2*W_ + 2*H_ + 255) / 256), blk, 0, stream,
                       imh, imw, tab);

    dim3 grd(BP_ / 256);
    hipLaunchKernelGGL(k_pass1, grd, blk, 0, stream,
                       depth, opacity, confidence, poses, tab,
                       keys, slots, entry_a, (uint32_t)(T - 1));
    hipLaunchKernelGGL(k_pass3, grd, blk, 0, stream,
                       depth, covariance, rotation, opacity, sh_color, confidence,
                       poses, tab, entry_a, slots, out);
}

// Round 5
// 307.267 us; speedup vs baseline: 1.7028x; 1.4487x over previous
//
#include <hip/hip_runtime.h>
#include <stdint.h>
#include <math.h>

#ifndef M_PI
#define M_PI 3.14159265358979323846
#endif

// Problem constants (fixed by setup_inputs)
#define B_ 2
#define N_ 4
#define H_ 256
#define W_ 512
#define C_ 12
#define HW_ (H_*W_)          // 131072 = 2^17
#define P_ (N_*HW_)          // 524288 = 2^19
#define BP_ (B_*P_)          // 1048576
#define INVALID_ENTRY 0xFFFFFFFFu

// pass1 blocking
#define CHUNK 1024           // points per block
#define PPT 4                // points per thread (256 thr)
#define LTAB 2048            // LDS combiner entries
#define LMASK (LTAB-1)
#define PROBE_MAX 8

__device__ __forceinline__ uint32_t mix32(uint32_t k) {
    k ^= k >> 16; k *= 0x85ebca6bu;
    k ^= k >> 13; k *= 0xc2b2ae35u;
    k ^= k >> 16;
    return k;
}

// Shared math: means + pk recomputed bit-identically in pass1 and pass3.
__device__ __forceinline__ void compute_means(
    int b, int n, float d, const float* __restrict__ tab,
    const float* __restrict__ poses, int h, int w, float m[3])
{
    float sin_lon  = tab[w];
    float cos_lon  = tab[W_ + w];
    float cos_lat  = tab[2*W_ + h];
    float sin_nlat = tab[2*W_ + H_ + h];

    float pc0 = __fmul_rn(d, __fmul_rn(cos_lat, sin_lon));
    float pc1 = __fmul_rn(d, sin_nlat);
    float pc2 = __fmul_rn(d, __fmul_rn(cos_lat, cos_lon));

    const float* Pz = poses + (size_t)(b * N_ + n) * 16;
#pragma unroll
    for (int i = 0; i < 3; ++i) {
        // einsum left-to-right, no FMA, then + t  (match jnp f32 semantics)
        float s = __fmul_rn(Pz[i*4+0], pc0);
        s = __fadd_rn(s, __fmul_rn(Pz[i*4+1], pc1));
        s = __fadd_rn(s, __fmul_rn(Pz[i*4+2], pc2));
        s = __fadd_rn(s, Pz[i*4+3]);
        m[i] = s;
    }
}

__device__ __forceinline__ unsigned long long make_pk(float conf, float opac, int p) {
    float score = __fadd_rn(__fmul_rn(0.7f, conf), __fmul_rn(0.3f, opac));
    // higher score wins; ties -> smaller per-batch index (stable-sort order)
    return ((unsigned long long)__float_as_uint(score) << 32)
         | (unsigned long long)(~(uint32_t)p);
}

__device__ __forceinline__ uint32_t voxel_key(const float m[3], int b) {
    int vc[3];
#pragma unroll
    for (int i = 0; i < 3; ++i) {
        float q  = __fdiv_rn(m[i], 0.1f);
        float fq = floorf(q);
        int vi = (int)fq + 512;
        vi = vi < 0 ? 0 : (vi > 1023 ? 1023 : vi);
        vc[i] = vi;
    }
    uint32_t vid = ((uint32_t)vc[0] << 20) | ((uint32_t)vc[1] << 10) | (uint32_t)vc[2];
    return vid | ((uint32_t)b << 30) | 0x80000000u;   // never 0
}

// Global find-or-insert, guarded (plain cached read first; CAS only on empty).
__device__ __forceinline__ uint32_t gfind(uint32_t* __restrict__ keys,
                                          uint32_t key, uint32_t tmask) {
    uint32_t slot = mix32(key) & tmask;
    while (true) {
        uint32_t k = keys[slot];
        if (k == key) return slot;
        if (k == 0u) {
            uint32_t prev = atomicCAS(&keys[slot], 0u, key);
            if (prev == 0u || prev == key) return slot;
        }
        slot = (slot + 1) & tmask;
    }
}

// Merge a local top-2 (a >= b, b may be 0) into the global slot pair.
// Guarded waterfall; stale-low plain reads are monotone-safe. The discarded
// min(displaced, b) can never be the true global 2nd max (requires two
// distinct values >= x2 neither being x1 -> contradiction).
__device__ __forceinline__ void gmerge(ulonglong2* __restrict__ slots, uint32_t slot,
                                       unsigned long long a, unsigned long long b) {
    ulonglong2 sp = slots[slot];
    unsigned long long low = a;
    if (a > sp.x) {
        unsigned long long old = atomicMax(&slots[slot].x, a);
        low = old < a ? old : a;          // displaced value
    }
    unsigned long long push = low > b ? low : b;
    if (push != 0ull && push > sp.y) atomicMax(&slots[slot].y, push);
}

// Pass 0: per-row/per-column trig tables (bitwise-identical hoist).
__global__ __launch_bounds__(256) void k_dirs(
    const int* __restrict__ p_imh, const int* __restrict__ p_imw,
    float* __restrict__ tab)
{
    int i = blockIdx.x * blockDim.x + threadIdx.x;
    int imh = *p_imh, imw = *p_imw;
    float fxf = (float)((double)imw / (2.0 * M_PI));
    float fyf = (float)(-(double)imh / M_PI);
    float cxf = (float)imw * 0.5f;
    float cyf = (float)imh * 0.5f;
    if (i < W_) {
        float lon = __fdiv_rn(__fsub_rn(__fadd_rn((float)i, 0.5f), cxf), fxf);
        double dlon = (double)lon;
        tab[i]       = (float)sin(dlon);
        tab[W_ + i]  = (float)cos(dlon);
    } else if (i < W_ + H_) {
        int h = i - W_;
        float lat = __fdiv_rn(__fsub_rn(__fadd_rn((float)h, 0.5f), cyf), fyf);
        double dlat = (double)lat;
        tab[2*W_ + h]       = (float)cos(dlat);
        tab[2*W_ + H_ + h]  = (float)sin(-dlat);
    }
}

// Pass 1: per-block LDS top-2 combiner, then one guarded global merge per
// distinct (block, voxel). Caps same-address global atomic chains ~20x.
__global__ __launch_bounds__(256) void k_pass1(
    const float* __restrict__ depth,
    const float* __restrict__ opacity,
    const float* __restrict__ confidence,
    const float* __restrict__ poses,
    const float* __restrict__ tab,
    uint32_t* __restrict__ keys,
    ulonglong2* __restrict__ slots,
    uint32_t* __restrict__ entry_arr,
    uint32_t tmask)
{
    __shared__ uint32_t           lkey[LTAB];
    __shared__ unsigned long long ls0[LTAB];
    __shared__ unsigned long long ls1[LTAB];
    __shared__ uint32_t           lgs[LTAB];

    for (int i = threadIdx.x; i < LTAB; i += 256) {
        lkey[i] = 0u; ls0[i] = 0ull; ls1[i] = 0ull;
    }
    __syncthreads();

    const int base = blockIdx.x * CHUNK;

    uint32_t           mykey[PPT];
    unsigned long long mypk[PPT];
    int                myl[PPT];     // >=0: LDS entry, -1: invalid, -2: overflow/direct

    // Phase A: compute + LDS combine
#pragma unroll
    for (int k = 0; k < PPT; ++k) {
        int g  = base + threadIdx.x + k * 256;
        int b  = g >> 19;
        int p  = g & (P_ - 1);
        int n  = p >> 17;
        int hw = p & (HW_ - 1);
        int h  = hw >> 9;
        int w  = hw & (W_ - 1);

        float conf = confidence[g];
        float opac = opacity[g];
        bool valid = (conf > 0.1f) && (opac > 0.01f);
        myl[k] = -1;
        if (!valid) continue;

        float m[3];
        compute_means(b, n, depth[g], tab, poses, h, w, m);
        uint32_t key = voxel_key(m, b);
        unsigned long long pk = make_pk(conf, opac, p);
        mykey[k] = key; mypk[k] = pk;

        uint32_t sl = mix32(key) & LMASK;
        int found = -1;
#pragma unroll 1
        for (int pr = 0; pr < PROBE_MAX; ++pr) {
            uint32_t kk = atomicCAS(&lkey[sl], 0u, key);
            if (kk == 0u || kk == key) { found = (int)sl; break; }
            sl = (sl + 1) & LMASK;
        }
        if (found >= 0) {
            unsigned long long old = atomicMax(&ls0[found], pk);
            unsigned long long low = old < pk ? old : pk;
            if (low != 0ull) atomicMax(&ls1[found], low);
            myl[k] = found;
        } else {
            myl[k] = -2;
        }
    }
    __syncthreads();

    // Phase B: merge occupied LDS entries into global table (dense, high MLP)
    for (int i = threadIdx.x; i < LTAB; i += 256) {
        uint32_t key = lkey[i];
        if (key == 0u) continue;
        uint32_t slot = gfind(keys, key, tmask);
        lgs[i] = slot;
        gmerge(slots, slot, ls0[i], ls1[i]);
    }
    __syncthreads();

    // Phase C: per-point entry write (+ direct path for LDS overflow)
#pragma unroll
    for (int k = 0; k < PPT; ++k) {
        int g = base + threadIdx.x + k * 256;
        uint32_t e;
        if (myl[k] == -1) {
            e = INVALID_ENTRY;
        } else if (myl[k] >= 0) {
            e = lgs[myl[k]];
        } else {
            uint32_t slot = gfind(keys, mykey[k], tmask);
            gmerge(slots, slot, mypk[k], 0ull);
            e = slot;
        }
        entry_arr[g] = e;
    }
}

// Pass 3: recompute means/pk, selection via slot pair, gather + write.
__global__ __launch_bounds__(256) void k_pass3(
    const float* __restrict__ depth,
    const float* __restrict__ covariance,
    const float* __restrict__ rotation,
    const float* __restrict__ opacity,
    const float* __restrict__ sh_color,
    const float* __restrict__ confidence,
    const float* __restrict__ poses,
    const float* __restrict__ tab,
    const uint32_t* __restrict__ entry_arr,
    const ulonglong2* __restrict__ slots,
    float* __restrict__ out)
{
    int g = blockIdx.x * blockDim.x + threadIdx.x;
    if (g >= BP_) return;
    int b  = g >> 19;
    int p  = g & (P_ - 1);
    int n  = p >> 17;
    int hw = p & (HW_ - 1);
    int h  = hw >> 9;
    int w  = hw & (W_ - 1);

    float conf = confidence[g];
    float opac = opacity[g];

    uint32_t e = entry_arr[g];
    bool sel = false;
    if (e != INVALID_ENTRY) {
        unsigned long long pk = make_pk(conf, opac, p);
        ulonglong2 sp = slots[e];
        sel = (pk == sp.x) || (pk == sp.y);
    }

    alignas(16) float v[24];
    if (sel) {
        float m[3];
        compute_means(b, n, depth[g], tab, poses, h, w, m);
        int bn = b * N_ + n;
        const float* cov = covariance + (size_t)bn * 3  * HW_ + hw;
        const float* rot = rotation   + (size_t)bn * 4  * HW_ + hw;
        const float* shc = sh_color   + (size_t)bn * 12 * HW_ + hw;
        v[0] = m[0]; v[1] = m[1]; v[2] = m[2];
        v[3] = cov[0]; v[4] = cov[HW_]; v[5] = cov[2*HW_];
        v[6] = rot[0]; v[7] = rot[HW_]; v[8] = rot[2*HW_]; v[9] = rot[3*HW_];
        v[10] = opac;
#pragma unroll
        for (int c = 0; c < 12; ++c) v[11 + c] = shc[(size_t)c * HW_];
        v[23] = conf;
    } else {
#pragma unroll
        for (int i = 0; i < 24; ++i) v[i] = 0.0f;
    }

    float4* o = (float4*)(out + (size_t)g * 24);
#pragma unroll
    for (int i = 0; i < 6; ++i) o[i] = ((const float4*)v)[i];

    out[(size_t)BP_ * 24 + g] = sel ? 1.0f : 0.0f;
}

extern "C" void kernel_launch(void* const* d_in, const int* in_sizes, int n_in,
                              void* d_out, int out_size, void* d_ws, size_t ws_size,
                              hipStream_t stream)
{
    const float* depth      = (const float*)d_in[0];
    const float* covariance = (const float*)d_in[1];
    const float* rotation   = (const float*)d_in[2];
    const float* opacity    = (const float*)d_in[3];
    const float* sh_color   = (const float*)d_in[4];
    const float* confidence = (const float*)d_in[5];
    const float* poses      = (const float*)d_in[6];
    const int*   imh        = (const int*)d_in[7];
    const int*   imw        = (const int*)d_in[8];
    float* out = (float*)d_out;

    // T = 2^20 >= max possible valid points, so the table can never overflow.
    size_t tab_bytes = (size_t)(2*W_ + 2*H_) * 4;
    size_t fixed_bytes = (size_t)BP_ * 4 + tab_bytes;
    size_t T = (size_t)1 << 20;
    while (T > ((size_t)1 << 18) && fixed_bytes + T * 20 > ws_size) T >>= 1;

    char* wp = (char*)d_ws;
    uint32_t* keys     = (uint32_t*)wp;   wp += T * 4;
    ulonglong2* slots  = (ulonglong2*)wp; wp += T * 16;
    uint32_t* entry_a  = (uint32_t*)wp;   wp += (size_t)BP_ * 4;
    float* tab = (float*)wp;              wp += tab_bytes;

    // keys empty = 0 and slots zero -> one contiguous memset (keys+slots adjacent)
    hipMemsetAsync(d_ws, 0x00, T * 20, stream);

    dim3 blk(256);
    hipLaunchKernelGGL(k_dirs, dim3((2*W_ + 2*H_ + 255) / 256), blk, 0, stream,
                       imh, imw, tab);

    hipLaunchKernelGGL(k_pass1, dim3(BP_ / CHUNK), blk, 0, stream,
                       depth, opacity, confidence, poses, tab,
                       keys, slots, entry_a, (uint32_t)(T - 1));
    hipLaunchKernelGGL(k_pass3, dim3(BP_ / 256), blk, 0, stream,
                       depth, covariance, rotation, opacity, sh_color, confidence,
                       poses, tab, entry_a, slots, out);
}

// Round 8
// 302.381 us; speedup vs baseline: 1.7303x; 1.0162x over previous
//
#include <hip/hip_runtime.h>
#include <stdint.h>
#include <math.h>

#ifndef M_PI
#define M_PI 3.14159265358979323846
#endif

// Problem constants (fixed by setup_inputs)
#define B_ 2
#define N_ 4
#define H_ 256
#define W_ 512
#define C_ 12
#define HW_ (H_*W_)          // 131072 = 2^17
#define P_ (N_*HW_)          // 524288 = 2^19
#define BP_ (B_*P_)          // 1048576
#define INVALID_ENTRY 0xFFFFFFFFu

// pass1 blocking
#define CHUNK 1024           // points per block
#define PPT 4                // points per thread (256 thr)
#define LTAB 2048            // LDS combiner entries
#define LMASK (LTAB-1)
#define PROBE_MAX 8

__device__ __forceinline__ uint32_t mix32(uint32_t k) {
    k ^= k >> 16; k *= 0x85ebca6bu;
    k ^= k >> 13; k *= 0xc2b2ae35u;
    k ^= k >> 16;
    return k;
}

// Shared math: means + pk recomputed bit-identically in pass1 and pass3.
__device__ __forceinline__ void compute_means_raw(
    int b, int n, float d, float sin_lon, float cos_lon, float cos_lat, float sin_nlat,
    const float* __restrict__ poses, float m[3])
{
    float pc0 = __fmul_rn(d, __fmul_rn(cos_lat, sin_lon));
    float pc1 = __fmul_rn(d, sin_nlat);
    float pc2 = __fmul_rn(d, __fmul_rn(cos_lat, cos_lon));

    const float* Pz = poses + (size_t)(b * N_ + n) * 16;
#pragma unroll
    for (int i = 0; i < 3; ++i) {
        // einsum left-to-right, no FMA, then + t  (match jnp f32 semantics)
        float s = __fmul_rn(Pz[i*4+0], pc0);
        s = __fadd_rn(s, __fmul_rn(Pz[i*4+1], pc1));
        s = __fadd_rn(s, __fmul_rn(Pz[i*4+2], pc2));
        s = __fadd_rn(s, Pz[i*4+3]);
        m[i] = s;
    }
}

__device__ __forceinline__ void compute_means(
    int b, int n, float d, const float* __restrict__ tab,
    const float* __restrict__ poses, int h, int w, float m[3])
{
    compute_means_raw(b, n, d, tab[w], tab[W_ + w], tab[2*W_ + h], tab[2*W_ + H_ + h],
                      poses, m);
}

__device__ __forceinline__ unsigned long long make_pk(float conf, float opac, int p) {
    float score = __fadd_rn(__fmul_rn(0.7f, conf), __fmul_rn(0.3f, opac));
    // higher score wins; ties -> smaller per-batch index (stable-sort order)
    return ((unsigned long long)__float_as_uint(score) << 32)
         | (unsigned long long)(~(uint32_t)p);
}

__device__ __forceinline__ uint32_t voxel_key(const float m[3], int b) {
    int vc[3];
#pragma unroll
    for (int i = 0; i < 3; ++i) {
        float q  = __fdiv_rn(m[i], 0.1f);
        float fq = floorf(q);
        int vi = (int)fq + 512;
        vi = vi < 0 ? 0 : (vi > 1023 ? 1023 : vi);
        vc[i] = vi;
    }
    uint32_t vid = ((uint32_t)vc[0] << 20) | ((uint32_t)vc[1] << 10) | (uint32_t)vc[2];
    return vid | ((uint32_t)b << 30) | 0x80000000u;   // never 0
}

// Global find-or-insert, guarded (plain cached read first; CAS only on empty).
__device__ __forceinline__ uint32_t gfind(uint32_t* __restrict__ keys,
                                          uint32_t key, uint32_t tmask) {
    uint32_t slot = mix32(key) & tmask;
    while (true) {
        uint32_t k = keys[slot];
        if (k == key) return slot;
        if (k == 0u) {
            uint32_t prev = atomicCAS(&keys[slot], 0u, key);
            if (prev == 0u || prev == key) return slot;
        }
        slot = (slot + 1) & tmask;
    }
}

// Merge a local top-2 (a >= b, b may be 0) into the global slot pair.
// Guarded waterfall; stale-low plain reads are monotone-safe. The discarded
// min(displaced, b) can never be the true global 2nd max.
__device__ __forceinline__ void gmerge(ulonglong2* __restrict__ slots, uint32_t slot,
                                       unsigned long long a, unsigned long long b) {
    ulonglong2 sp = slots[slot];
    unsigned long long low = a;
    if (a > sp.x) {
        unsigned long long old = atomicMax(&slots[slot].x, a);
        low = old < a ? old : a;          // displaced value
    }
    unsigned long long push = low > b ? low : b;
    if (push != 0ull && push > sp.y) atomicMax(&slots[slot].y, push);
}

// Pass 0: per-row/per-column trig tables (bitwise-identical hoist).
__global__ __launch_bounds__(256) void k_dirs(
    const int* __restrict__ p_imh, const int* __restrict__ p_imw,
    float* __restrict__ tab)
{
    int i = blockIdx.x * blockDim.x + threadIdx.x;
    int imh = *p_imh, imw = *p_imw;
    float fxf = (float)((double)imw / (2.0 * M_PI));
    float fyf = (float)(-(double)imh / M_PI);
    float cxf = (float)imw * 0.5f;
    float cyf = (float)imh * 0.5f;
    if (i < W_) {
        float lon = __fdiv_rn(__fsub_rn(__fadd_rn((float)i, 0.5f), cxf), fxf);
        double dlon = (double)lon;
        tab[i]       = (float)sin(dlon);
        tab[W_ + i]  = (float)cos(dlon);
    } else if (i < W_ + H_) {
        int h = i - W_;
        float lat = __fdiv_rn(__fsub_rn(__fadd_rn((float)h, 0.5f), cyf), fyf);
        double dlat = (double)lat;
        tab[2*W_ + h]       = (float)cos(dlat);
        tab[2*W_ + H_ + h]  = (float)sin(-dlat);
    }
}

// Pass 1: per-block LDS top-2 combiner, then one guarded global merge per
// distinct (block, voxel). lkey is reused to forward global slot to phase C.
__global__ __launch_bounds__(256) void k_pass1(
    const float* __restrict__ depth,
    const float* __restrict__ opacity,
    const float* __restrict__ confidence,
    const float* __restrict__ poses,
    const float* __restrict__ tab,
    uint32_t* __restrict__ keys,
    ulonglong2* __restrict__ slots,
    uint32_t* __restrict__ entry_arr,
    uint32_t tmask)
{
    __shared__ uint32_t           lkey[LTAB];   // phase A: key, phase B/C: global slot
    __shared__ unsigned long long ls0[LTAB];
    __shared__ unsigned long long ls1[LTAB];

    for (int i = threadIdx.x; i < LTAB; i += 256) {
        lkey[i] = 0u; ls0[i] = 0ull; ls1[i] = 0ull;
    }
    __syncthreads();

    const int base = blockIdx.x * CHUNK;

    uint32_t           mykey[PPT];
    unsigned long long mypk[PPT];
    int                myl[PPT];     // >=0: LDS entry, -1: invalid, -2: overflow/direct

    // Phase A: compute + LDS combine
#pragma unroll
    for (int k = 0; k < PPT; ++k) {
        int g  = base + threadIdx.x + k * 256;
        int b  = g >> 19;
        int p  = g & (P_ - 1);
        int n  = p >> 17;
        int hw = p & (HW_ - 1);
        int h  = hw >> 9;
        int w  = hw & (W_ - 1);

        float conf = confidence[g];
        float opac = opacity[g];
        bool valid = (conf > 0.1f) && (opac > 0.01f);
        myl[k] = -1;
        if (!valid) continue;

        float m[3];
        compute_means(b, n, depth[g], tab, poses, h, w, m);
        uint32_t key = voxel_key(m, b);
        unsigned long long pk = make_pk(conf, opac, p);
        mykey[k] = key; mypk[k] = pk;

        uint32_t sl = mix32(key) & LMASK;
        int found = -1;
#pragma unroll 1
        for (int pr = 0; pr < PROBE_MAX; ++pr) {
            uint32_t kk = atomicCAS(&lkey[sl], 0u, key);
            if (kk == 0u || kk == key) { found = (int)sl; break; }
            sl = (sl + 1) & LMASK;
        }
        if (found >= 0) {
            unsigned long long old = atomicMax(&ls0[found], pk);
            unsigned long long low = old < pk ? old : pk;
            if (low != 0ull) atomicMax(&ls1[found], low);
            myl[k] = found;
        } else {
            myl[k] = -2;
        }
    }
    __syncthreads();

    // Phase B: merge occupied LDS entries into global table; overwrite lkey
    // with the global slot (disjoint per-thread indices, barrier-separated).
    for (int i = threadIdx.x; i < LTAB; i += 256) {
        uint32_t key = lkey[i];
        if (key == 0u) continue;
        uint32_t slot = gfind(keys, key, tmask);
        gmerge(slots, slot, ls0[i], ls1[i]);
        lkey[i] = slot;
    }
    __syncthreads();

    // Phase C: per-point entry write (+ direct path for LDS overflow)
#pragma unroll
    for (int k = 0; k < PPT; ++k) {
        int g = base + threadIdx.x + k * 256;
        uint32_t e;
        if (myl[k] == -1) {
            e = INVALID_ENTRY;
        } else if (myl[k] >= 0) {
            e = lkey[myl[k]];
        } else {
            uint32_t slot = gfind(keys, mykey[k], tmask);
            gmerge(slots, slot, mypk[k], 0ull);
            e = slot;
        }
        entry_arr[g] = e;
    }
}

// Pass 3: branch-free streaming. 4 points/thread, float4 loads per channel,
// compute all 24 features, multiply by 0/1 mask (exactly what the reference
// does: feat * sel), store 384B contiguous per thread + 4 flags.
__global__ __launch_bounds__(256) void k_pass3(
    const float* __restrict__ depth,
    const float* __restrict__ covariance,
    const float* __restrict__ rotation,
    const float* __restrict__ opacity,
    const float* __restrict__ sh_color,
    const float* __restrict__ confidence,
    const float* __restrict__ poses,
    const float* __restrict__ tab,
    const uint32_t* __restrict__ entry_arr,
    const ulonglong2* __restrict__ slots,
    float* __restrict__ out)
{
    int t = blockIdx.x * blockDim.x + threadIdx.x;   // 0 .. BP_/4
    int g0 = t * 4;
    if (g0 >= BP_) return;
    int b   = g0 >> 19;
    int p0  = g0 & (P_ - 1);
    int n   = p0 >> 17;
    int hw0 = p0 & (HW_ - 1);
    int h   = hw0 >> 9;
    int w0  = hw0 & (W_ - 1);        // multiple of 4; row never crossed (W_%4==0)
    int bn  = b * N_ + n;            // same for all 4 points

    const float4 d4  = *(const float4*)&depth[g0];
    const float4 cf4 = *(const float4*)&confidence[g0];
    const float4 op4 = *(const float4*)&opacity[g0];
    const uint4  e4  = *(const uint4*)&entry_arr[g0];

    const float4 sl4 = *(const float4*)&tab[w0];        // sin_lon
    const float4 cl4 = *(const float4*)&tab[W_ + w0];   // cos_lon
    const float cos_lat  = tab[2*W_ + h];
    const float sin_nlat = tab[2*W_ + H_ + h];

    const float* cov = covariance + (size_t)bn * 3  * HW_ + hw0;
    const float* rot = rotation   + (size_t)bn * 4  * HW_ + hw0;
    const float* shc = sh_color   + (size_t)bn * 12 * HW_ + hw0;

    float4 cv[3], rt[4], sh[12];
#pragma unroll
    for (int c = 0; c < 3; ++c)  cv[c] = *(const float4*)&cov[(size_t)c * HW_];
#pragma unroll
    for (int c = 0; c < 4; ++c)  rt[c] = *(const float4*)&rot[(size_t)c * HW_];
#pragma unroll
    for (int c = 0; c < 12; ++c) sh[c] = *(const float4*)&shc[(size_t)c * HW_];

    float msk[4];
#pragma unroll
    for (int i = 0; i < 4; ++i) {
        int p = p0 + i;
        float conf = ((const float*)&cf4)[i];
        float opac = ((const float*)&op4)[i];
        uint32_t e = ((const uint32_t*)&e4)[i];
        bool sel = false;
        if (e != INVALID_ENTRY) {
            unsigned long long pk = make_pk(conf, opac, p);
            ulonglong2 sp = slots[e];
            sel = (pk == sp.x) || (pk == sp.y);
        }
        msk[i] = sel ? 1.0f : 0.0f;

        float m[3];
        compute_means_raw(b, n, ((const float*)&d4)[i],
                          ((const float*)&sl4)[i], ((const float*)&cl4)[i],
                          cos_lat, sin_nlat, poses, m);

        alignas(16) float v[24];
        v[0] = m[0] * msk[i]; v[1] = m[1] * msk[i]; v[2] = m[2] * msk[i];
#pragma unroll
        for (int c = 0; c < 3; ++c)  v[3 + c]  = ((const float*)&cv[c])[i] * msk[i];
#pragma unroll
        for (int c = 0; c < 4; ++c)  v[6 + c]  = ((const float*)&rt[c])[i] * msk[i];
        v[10] = opac * msk[i];
#pragma unroll
        for (int c = 0; c < 12; ++c) v[11 + c] = ((const float*)&sh[c])[i] * msk[i];
        v[23] = conf * msk[i];

        float4* o = (float4*)(out + (size_t)(g0 + i) * 24);
#pragma unroll
        for (int q = 0; q < 6; ++q) o[q] = ((const float4*)v)[q];
    }

    *(float4*)&out[(size_t)BP_ * 24 + g0] = make_float4(msk[0], msk[1], msk[2], msk[3]);
}

extern "C" void kernel_launch(void* const* d_in, const int* in_sizes, int n_in,
                              void* d_out, int out_size, void* d_ws, size_t ws_size,
                              hipStream_t stream)
{
    const float* depth      = (const float*)d_in[0];
    const float* covariance = (const float*)d_in[1];
    const float* rotation   = (const float*)d_in[2];
    const float* opacity    = (const float*)d_in[3];
    const float* sh_color   = (const float*)d_in[4];
    const float* confidence = (const float*)d_in[5];
    const float* poses      = (const float*)d_in[6];
    const int*   imh        = (const int*)d_in[7];
    const int*   imw        = (const int*)d_in[8];
    float* out = (float*)d_out;

    // T = 2^20 >= max possible valid points, so the table can never overflow.
    size_t tab_bytes = (size_t)(2*W_ + 2*H_) * 4;
    size_t fixed_bytes = (size_t)BP_ * 4 + tab_bytes;
    size_t T = (size_t)1 << 20;
    while (T > ((size_t)1 << 18) && fixed_bytes + T * 20 > ws_size) T >>= 1;

    char* wp = (char*)d_ws;
    uint32_t* keys     = (uint32_t*)wp;   wp += T * 4;
    ulonglong2* slots  = (ulonglong2*)wp; wp += T * 16;
    uint32_t* entry_a  = (uint32_t*)wp;   wp += (size_t)BP_ * 4;
    float* tab = (float*)wp;              wp += tab_bytes;

    // keys empty = 0 and slots zero -> one contiguous memset (keys+slots adjacent)
    hipMemsetAsync(d_ws, 0x00, T * 20, stream);

    dim3 blk(256);
    hipLaunchKernelGGL(k_dirs, dim3((2*W_ + 2*H_ + 255) / 256), blk, 0, stream,
                       imh, imw, tab);

    hipLaunchKernelGGL(k_pass1, dim3(BP_ / CHUNK), blk, 0, stream,
                       depth, opacity, confidence, poses, tab,
                       keys, slots, entry_a, (uint32_t)(T - 1));
    hipLaunchKernelGGL(k_pass3, dim3(BP_ / 4 / 256), blk, 0, stream,
                       depth, covariance, rotation, opacity, sh_color, confidence,
                       poses, tab, entry_a, slots, out);
}

// Round 14
// 262.533 us; speedup vs baseline: 1.9930x; 1.1518x over previous
//
#include <hip/hip_runtime.h>
#include <stdint.h>
#include <math.h>

#ifndef M_PI
#define M_PI 3.14159265358979323846
#endif

// Problem constants (fixed by setup_inputs)
#define B_ 2
#define N_ 4
#define H_ 256
#define W_ 512
#define C_ 12
#define HW_ (H_*W_)          // 131072 = 2^17
#define P_ (N_*HW_)          // 524288 = 2^19
#define BP_ (B_*P_)          // 1048576
#define INVALID_ENTRY 0xFFFFFFFFu

// pass1 blocking
#define CHUNK 1024           // points per block
#define PPT 4                // points per thread (256 thr)
#define LTAB 2048            // LDS combiner entries
#define LMASK (LTAB-1)
#define PROBE_MAX 8

typedef float fx4 __attribute__((ext_vector_type(4)));   // native vector for nontemporal stores

__device__ __forceinline__ uint32_t mix32(uint32_t k) {
    k ^= k >> 16; k *= 0x85ebca6bu;
    k ^= k >> 13; k *= 0xc2b2ae35u;
    k ^= k >> 16;
    return k;
}

// Shared math: means + pk recomputed bit-identically in pass1 and pass3.
__device__ __forceinline__ void compute_means_raw(
    int b, int n, float d, float sin_lon, float cos_lon, float cos_lat, float sin_nlat,
    const float* __restrict__ poses, float m[3])
{
    float pc0 = __fmul_rn(d, __fmul_rn(cos_lat, sin_lon));
    float pc1 = __fmul_rn(d, sin_nlat);
    float pc2 = __fmul_rn(d, __fmul_rn(cos_lat, cos_lon));

    const float* Pz = poses + (size_t)(b * N_ + n) * 16;
#pragma unroll
    for (int i = 0; i < 3; ++i) {
        // einsum left-to-right, no FMA, then + t  (match jnp f32 semantics)
        float s = __fmul_rn(Pz[i*4+0], pc0);
        s = __fadd_rn(s, __fmul_rn(Pz[i*4+1], pc1));
        s = __fadd_rn(s, __fmul_rn(Pz[i*4+2], pc2));
        s = __fadd_rn(s, Pz[i*4+3]);
        m[i] = s;
    }
}

__device__ __forceinline__ void compute_means(
    int b, int n, float d, const float* __restrict__ tab,
    const float* __restrict__ poses, int h, int w, float m[3])
{
    compute_means_raw(b, n, d, tab[w], tab[W_ + w], tab[2*W_ + h], tab[2*W_ + H_ + h],
                      poses, m);
}

__device__ __forceinline__ unsigned long long make_pk(float conf, float opac, int p) {
    float score = __fadd_rn(__fmul_rn(0.7f, conf), __fmul_rn(0.3f, opac));
    // higher score wins; ties -> smaller per-batch index (stable-sort order)
    return ((unsigned long long)__float_as_uint(score) << 32)
         | (unsigned long long)(~(uint32_t)p);
}

__device__ __forceinline__ uint32_t voxel_key(const float m[3], int b) {
    int vc[3];
#pragma unroll
    for (int i = 0; i < 3; ++i) {
        float q  = __fdiv_rn(m[i], 0.1f);
        float fq = floorf(q);
        int vi = (int)fq + 512;
        vi = vi < 0 ? 0 : (vi > 1023 ? 1023 : vi);
        vc[i] = vi;
    }
    uint32_t vid = ((uint32_t)vc[0] << 20) | ((uint32_t)vc[1] << 10) | (uint32_t)vc[2];
    return vid | ((uint32_t)b << 30) | 0x80000000u;   // never 0
}

// Global find-or-insert, guarded (plain cached read first; CAS only on empty).
__device__ __forceinline__ uint32_t gfind(uint32_t* __restrict__ keys,
                                          uint32_t key, uint32_t tmask) {
    uint32_t slot = mix32(key) & tmask;
    while (true) {
        uint32_t k = keys[slot];
        if (k == key) return slot;
        if (k == 0u) {
            uint32_t prev = atomicCAS(&keys[slot], 0u, key);
            if (prev == 0u || prev == key) return slot;
        }
        slot = (slot + 1) & tmask;
    }
}

// Merge a local top-2 (a >= b, b may be 0) into the global slot pair.
// Guarded waterfall; stale-low plain reads are monotone-safe. The discarded
// min(displaced, b) can never be the true global 2nd max.
__device__ __forceinline__ void gmerge(ulonglong2* __restrict__ slots, uint32_t slot,
                                       unsigned long long a, unsigned long long b) {
    ulonglong2 sp = slots[slot];
    unsigned long long low = a;
    if (a > sp.x) {
        unsigned long long old = atomicMax(&slots[slot].x, a);
        low = old < a ? old : a;          // displaced value
    }
    unsigned long long push = low > b ? low : b;
    if (push != 0ull && push > sp.y) atomicMax(&slots[slot].y, push);
}

// Pass 0: per-row/per-column trig tables (bitwise-identical hoist).
__global__ __launch_bounds__(256) void k_dirs(
    const int* __restrict__ p_imh, const int* __restrict__ p_imw,
    float* __restrict__ tab)
{
    int i = blockIdx.x * blockDim.x + threadIdx.x;
    int imh = *p_imh, imw = *p_imw;
    float fxf = (float)((double)imw / (2.0 * M_PI));
    float fyf = (float)(-(double)imh / M_PI);
    float cxf = (float)imw * 0.5f;
    float cyf = (float)imh * 0.5f;
    if (i < W_) {
        float lon = __fdiv_rn(__fsub_rn(__fadd_rn((float)i, 0.5f), cxf), fxf);
        double dlon = (double)lon;
        tab[i]       = (float)sin(dlon);
        tab[W_ + i]  = (float)cos(dlon);
    } else if (i < W_ + H_) {
        int h = i - W_;
        float lat = __fdiv_rn(__fsub_rn(__fadd_rn((float)h, 0.5f), cyf), fyf);
        double dlat = (double)lat;
        tab[2*W_ + h]       = (float)cos(dlat);
        tab[2*W_ + H_ + h]  = (float)sin(-dlat);
    }
}

// Pass 1: per-block LDS top-2 combiner, then one guarded global merge per
// distinct (block, voxel). lkey is reused to forward global slot to phase C.
__global__ __launch_bounds__(256) void k_pass1(
    const float* __restrict__ depth,
    const float* __restrict__ opacity,
    const float* __restrict__ confidence,
    const float* __restrict__ poses,
    const float* __restrict__ tab,
    uint32_t* __restrict__ keys,
    ulonglong2* __restrict__ slots,
    uint32_t* __restrict__ entry_arr,
    uint32_t tmask)
{
    __shared__ uint32_t           lkey[LTAB];   // phase A: key, phase B/C: global slot
    __shared__ unsigned long long ls0[LTAB];
    __shared__ unsigned long long ls1[LTAB];

    for (int i = threadIdx.x; i < LTAB; i += 256) {
        lkey[i] = 0u; ls0[i] = 0ull; ls1[i] = 0ull;
    }
    __syncthreads();

    const int base = blockIdx.x * CHUNK;

    uint32_t           mykey[PPT];
    unsigned long long mypk[PPT];
    int                myl[PPT];     // >=0: LDS entry, -1: invalid, -2: overflow/direct

    // Phase A: compute + LDS combine
#pragma unroll
    for (int k = 0; k < PPT; ++k) {
        int g  = base + threadIdx.x + k * 256;
        int b  = g >> 19;
        int p  = g & (P_ - 1);
        int n  = p >> 17;
        int hw = p & (HW_ - 1);
        int h  = hw >> 9;
        int w  = hw & (W_ - 1);

        float conf = confidence[g];
        float opac = opacity[g];
        bool valid = (conf > 0.1f) && (opac > 0.01f);
        myl[k] = -1;
        if (!valid) continue;

        float m[3];
        compute_means(b, n, depth[g], tab, poses, h, w, m);
        uint32_t key = voxel_key(m, b);
        unsigned long long pk = make_pk(conf, opac, p);
        mykey[k] = key; mypk[k] = pk;

        uint32_t sl = mix32(key) & LMASK;
        int found = -1;
#pragma unroll 1
        for (int pr = 0; pr < PROBE_MAX; ++pr) {
            uint32_t kk = atomicCAS(&lkey[sl], 0u, key);
            if (kk == 0u || kk == key) { found = (int)sl; break; }
            sl = (sl + 1) & LMASK;
        }
        if (found >= 0) {
            unsigned long long old = atomicMax(&ls0[found], pk);
            unsigned long long low = old < pk ? old : pk;
            if (low != 0ull) atomicMax(&ls1[found], low);
            myl[k] = found;
        } else {
            myl[k] = -2;
        }
    }
    __syncthreads();

    // Phase B: merge occupied LDS entries into global table; overwrite lkey
    // with the global slot (disjoint per-thread indices, barrier-separated).
    for (int i = threadIdx.x; i < LTAB; i += 256) {
        uint32_t key = lkey[i];
        if (key == 0u) continue;
        uint32_t slot = gfind(keys, key, tmask);
        gmerge(slots, slot, ls0[i], ls1[i]);
        lkey[i] = slot;
    }
    __syncthreads();

    // Phase C: per-point entry write (+ direct path for LDS overflow)
#pragma unroll
    for (int k = 0; k < PPT; ++k) {
        int g = base + threadIdx.x + k * 256;
        uint32_t e;
        if (myl[k] == -1) {
            e = INVALID_ENTRY;
        } else if (myl[k] >= 0) {
            e = lkey[myl[k]];
        } else {
            uint32_t slot = gfind(keys, mykey[k], tmask);
            gmerge(slots, slot, mypk[k], 0ull);
            e = slot;
        }
        entry_arr[g] = e;
    }
}

// Pass 3: 1 point/thread, 256 points/block. Compute masked features into a
// transposed LDS stage st[25][256] (conflict-free stride-256 writes), then
// stream the block's 24KB output region as 6 fully-coalesced float4 stores
// per thread (4KB contiguous per instruction) + one coalesced flag row.
// Loads are scalar but lane-contiguous (channel-major inputs).
__global__ __launch_bounds__(256) void k_pass3(
    const float* __restrict__ depth,
    const float* __restrict__ covariance,
    const float* __restrict__ rotation,
    const float* __restrict__ opacity,
    const float* __restrict__ sh_color,
    const float* __restrict__ confidence,
    const float* __restrict__ poses,
    const float* __restrict__ tab,
    const uint32_t* __restrict__ entry_arr,
    const ulonglong2* __restrict__ slots,
    float* __restrict__ out)
{
    __shared__ float st[25 * 256];   // [channel][point-in-block], 25.6 KB

    const int tid = threadIdx.x;
    const int g   = blockIdx.x * 256 + tid;    // grid = BP_/256, always < BP_
    int b  = g >> 19;
    int p  = g & (P_ - 1);
    int n  = p >> 17;
    int hw = p & (HW_ - 1);
    int h  = hw >> 9;
    int w  = hw & (W_ - 1);
    int bn = b * N_ + n;

    float d    = depth[g];
    float conf = confidence[g];
    float opac = opacity[g];
    uint32_t e = entry_arr[g];

    bool sel = false;
    if (e != INVALID_ENTRY) {
        unsigned long long pk = make_pk(conf, opac, p);
        ulonglong2 sp = slots[e];
        sel = (pk == sp.x) || (pk == sp.y);
    }
    float msk = sel ? 1.0f : 0.0f;

    float m[3];
    compute_means(b, n, d, tab, poses, h, w, m);

    const float* cov = covariance + (size_t)bn * 3  * HW_ + hw;
    const float* rot = rotation   + (size_t)bn * 4  * HW_ + hw;
    const float* shc = sh_color   + (size_t)bn * 12 * HW_ + hw;

    st[0*256 + tid] = m[0] * msk;
    st[1*256 + tid] = m[1] * msk;
    st[2*256 + tid] = m[2] * msk;
#pragma unroll
    for (int c = 0; c < 3; ++c)  st[(3 + c)*256 + tid]  = cov[(size_t)c * HW_] * msk;
#pragma unroll
    for (int c = 0; c < 4; ++c)  st[(6 + c)*256 + tid]  = rot[(size_t)c * HW_] * msk;
    st[10*256 + tid] = opac * msk;
#pragma unroll
    for (int c = 0; c < 12; ++c) st[(11 + c)*256 + tid] = shc[(size_t)c * HW_] * msk;
    st[23*256 + tid] = conf * msk;
    st[24*256 + tid] = msk;

    __syncthreads();

    // Coalesced writeout: block's features = 1536 float4s starting at
    // out + blockIdx.x*256*24. float4 #k covers point k/6, channels (k%6)*4...
    fx4* obase = (fx4*)(out + (size_t)blockIdx.x * 256 * 24);
#pragma unroll
    for (int s = 0; s < 6; ++s) {
        int k = s * 256 + tid;
        int pt = k / 6;
        int oq = k - pt * 6;
        fx4 f;
        f.x = st[(oq*4 + 0)*256 + pt];
        f.y = st[(oq*4 + 1)*256 + pt];
        f.z = st[(oq*4 + 2)*256 + pt];
        f.w = st[(oq*4 + 3)*256 + pt];
        __builtin_nontemporal_store(f, &obase[k]);
    }
    __builtin_nontemporal_store(st[24*256 + tid], &out[(size_t)BP_ * 24 + g]);
}

extern "C" void kernel_launch(void* const* d_in, const int* in_sizes, int n_in,
                              void* d_out, int out_size, void* d_ws, size_t ws_size,
                              hipStream_t stream)
{
    const float* depth      = (const float*)d_in[0];
    const float* covariance = (const float*)d_in[1];
    const float* rotation   = (const float*)d_in[2];
    const float* opacity    = (const float*)d_in[3];
    const float* sh_color   = (const float*)d_in[4];
    const float* confidence = (const float*)d_in[5];
    const float* poses      = (const float*)d_in[6];
    const int*   imh        = (const int*)d_in[7];
    const int*   imw        = (const int*)d_in[8];
    float* out = (float*)d_out;

    // T = 2^20 >= max possible valid points, so the table can never overflow.
    size_t tab_bytes = (size_t)(2*W_ + 2*H_) * 4;
    size_t fixed_bytes = (size_t)BP_ * 4 + tab_bytes;
    size_t T = (size_t)1 << 20;
    while (T > ((size_t)1 << 18) && fixed_bytes + T * 20 > ws_size) T >>= 1;

    char* wp = (char*)d_ws;
    uint32_t* keys     = (uint32_t*)wp;   wp += T * 4;
    ulonglong2* slots  = (ulonglong2*)wp; wp += T * 16;
    uint32_t* entry_a  = (uint32_t*)wp;   wp += (size_t)BP_ * 4;
    float* tab = (float*)wp;              wp += tab_bytes;

    // keys empty = 0 and slots zero -> one contiguous memset (keys+slots adjacent)
    (void)hipMemsetAsync(d_ws, 0x00, T * 20, stream);

    dim3 blk(256);
    hipLaunchKernelGGL(k_dirs, dim3((2*W_ + 2*H_ + 255) / 256), blk, 0, stream,
                       imh, imw, tab);

    hipLaunchKernelGGL(k_pass1, dim3(BP_ / CHUNK), blk, 0, stream,
                       depth, opacity, confidence, poses, tab,
                       keys, slots, entry_a, (uint32_t)(T - 1));
    hipLaunchKernelGGL(k_pass3, dim3(BP_ / 256), blk, 0, stream,
                       depth, covariance, rotation, opacity, sh_color, confidence,
                       poses, tab, entry_a, slots, out);
}